// Round 5
// baseline (112.836 us; speedup 1.0000x reference)
//
#include <hip/hip_runtime.h>
#include <math.h>

constexpr int C = 120;
constexpr int B = 4096;
constexpr float EPS = 1e-5f;

typedef float f32x4 __attribute__((ext_vector_type(4)));

// out[b,c] = sqrt( eps + 384*eps^2 + sum over 24 slices of 0.5*sum_{k<i} d_ki^2 )
// d_ki = sum_j ( w[j][s][i]*x[j][s][k] - w[j][s][k]*x[j][s][i] )
//
// lane = r*8 + f8; r = (c,b) pair within group of 8, f8 = slice s.
// 1024 blocks * 4 waves * 120 pairs = 491520 = C*B.  launch_bounds(256,4)
// caps VGPR<=128 so exactly 4 blocks/CU are resident: zero scheduling tail.
__global__ __launch_bounds__(256, 4) void ttfc_kernel(
    const f32x4* __restrict__ x0,    // [C*B * 8]      ([c,b][s][i])
    const f32x4* __restrict__ x12,   // [2 * C*B * 32] ([g][c,b][j][s][i])
    const f32x4* __restrict__ w0,    // [8]   ([s][k])
    const f32x4* __restrict__ w12,   // [64]  ([g][j][s][k])
    float* __restrict__ out)         // [B,C]
{
    __shared__ f32x4 wl0[8];
    __shared__ f32x4 wl12[64];
    {
        int t = threadIdx.x;
        if (t < 8)  wl0[t]  = w0[t];
        if (t < 64) wl12[t] = w12[t];
    }
    __syncthreads();

    const int lane = threadIdx.x & 63;
    const int r    = lane >> 3;
    const int f8   = lane & 7;
    const int wv   = (blockIdx.x * blockDim.x + threadIdx.x) >> 6;  // global wave id
    const int wavebase = wv * 120;     // 120 (c,b) pairs per wave

    const f32x4 wc0 = wl0[f8];
    f32x4 wc12[2][4];
#pragma unroll
    for (int g = 0; g < 2; ++g)
#pragma unroll
        for (int p = 0; p < 4; ++p)
            wc12[g][p] = wl12[g * 32 + p * 8 + f8];

#pragma unroll 2
    for (int t = 0; t < 15; ++t) {
        const int idx = wavebase + t * 8 + r;     // this lane's (c,b)
        float cnt;

        // ---- core0: fully contiguous, 1 KiB per wave instruction ----
        {
            f32x4 x = x0[(size_t)(wavebase + t * 8) * 8 + lane];   // = idx*8 + f8
            f32x4 w = wc0;
            float d01 = w.y*x.x - w.x*x.y;
            float d02 = w.z*x.x - w.x*x.z;
            float d03 = w.w*x.x - w.x*x.w;
            float d12 = w.z*x.y - w.y*x.z;
            float d13 = w.w*x.y - w.y*x.w;
            float d23 = w.w*x.z - w.z*x.w;
            cnt = 0.5f*(d01*d01 + d02*d02 + d03*d03 + d12*d12 + d13*d13 + d23*d23);
        }

        // ---- core1/core2: 8 x 128B dense segments per instruction ----
#pragma unroll
        for (int g = 0; g < 2; ++g) {
            const f32x4* xp = x12 + (size_t)g * (C * B * 32) + (size_t)idx * 32 + f8;
            float d01 = 0.f, d02 = 0.f, d03 = 0.f, d12 = 0.f, d13 = 0.f, d23 = 0.f;
#pragma unroll
            for (int p = 0; p < 4; ++p) {        // p = j, accumulates in-lane
                f32x4 x = xp[p * 8];
                f32x4 w = wc12[g][p];
                d01 += w.y*x.x - w.x*x.y;
                d02 += w.z*x.x - w.x*x.z;
                d03 += w.w*x.x - w.x*x.w;
                d12 += w.z*x.y - w.y*x.z;
                d13 += w.w*x.y - w.y*x.w;
                d23 += w.w*x.z - w.z*x.w;
            }
            cnt += 0.5f*(d01*d01 + d02*d02 + d03*d03 + d12*d12 + d13*d13 + d23*d23);
        }

        // ---- reduce over s (8 lanes) ----
        cnt += __shfl_xor(cnt, 1);
        cnt += __shfl_xor(cnt, 2);
        cnt += __shfl_xor(cnt, 4);

        if (f8 == 0) {
            int c = idx >> 12;          // / 4096
            int b = idx & (B - 1);
            out[(size_t)b * C + c] = sqrtf(cnt + 384.0f * (EPS * EPS) + EPS);
        }
    }
}

extern "C" void kernel_launch(void* const* d_in, const int* in_sizes, int n_in,
                              void* d_out, int out_size, void* d_ws, size_t ws_size,
                              hipStream_t stream) {
    const f32x4* x0  = (const f32x4*)d_in[0];
    const f32x4* x12 = (const f32x4*)d_in[1];
    const f32x4* w0  = (const f32x4*)d_in[2];
    const f32x4* w12 = (const f32x4*)d_in[3];
    float* out = (float*)d_out;

    // 1024 blocks * 4 waves * 120 pairs = 491520 = C*B; 4 blocks/CU resident.
    hipLaunchKernelGGL(ttfc_kernel, dim3(1024), dim3(256), 0, stream,
                       x0, x12, w0, w12, out);
}

// Round 6
// 101.009 us; speedup vs baseline: 1.1171x; 1.1171x over previous
//
#include <hip/hip_runtime.h>
#include <math.h>

constexpr int C = 120;
constexpr int B = 4096;
constexpr float EPS = 1e-5f;

typedef float f32x4 __attribute__((ext_vector_type(4)));

// out[b,c] = sqrt( eps + 384*eps^2 + sum over 24 slices of 0.5*sum_{k<i} d_ki^2 )
// d_ki = sum_j ( w[j][s][i]*x[j][s][k] - w[j][s][k]*x[j][s][i] )
//
// lane = r*8 + f8; r = (c,b) pair within group of 8, f8 = slice s.
// Each wave handles 80 pairs (10 iters of 8). 1536 blocks = 6 per CU exactly.
// NOTE (R5 lesson): do NOT add __launch_bounds__ min-wave or shrink the grid —
// capping VGPR throttles the compiler's in-flight load window and regressed
// 101 -> 113 us. nt loads + unroll 2 + 1536 blocks is the measured optimum.
__global__ __launch_bounds__(256) void ttfc_kernel(
    const f32x4* __restrict__ x0,    // [C*B * 8]      ([c,b][s][i])
    const f32x4* __restrict__ x12,   // [2 * C*B * 32] ([g][c,b][j][s][i])
    const f32x4* __restrict__ w0,    // [8]   ([s][k])
    const f32x4* __restrict__ w12,   // [64]  ([g][j][s][k])
    float* __restrict__ out)         // [B,C]
{
    __shared__ f32x4 wl0[8];
    __shared__ f32x4 wl12[64];
    {
        int t = threadIdx.x;
        if (t < 8)  wl0[t]  = w0[t];
        if (t < 64) wl12[t] = w12[t];
    }
    __syncthreads();

    const int lane = threadIdx.x & 63;
    const int r    = lane >> 3;
    const int f8   = lane & 7;
    const int wv   = (blockIdx.x * blockDim.x + threadIdx.x) >> 6;  // global wave id
    const int wavebase = wv * 80;      // 80 (c,b) pairs per wave

    const f32x4 wc0 = wl0[f8];
    f32x4 wc12[2][4];
#pragma unroll
    for (int g = 0; g < 2; ++g)
#pragma unroll
        for (int p = 0; p < 4; ++p)
            wc12[g][p] = wl12[g * 32 + p * 8 + f8];

#pragma unroll 2
    for (int t = 0; t < 10; ++t) {
        const int idx = wavebase + t * 8 + r;     // this lane's (c,b)
        float cnt;

        // ---- core0: fully contiguous, 1 KiB per wave instruction ----
        {
            f32x4 x = __builtin_nontemporal_load(
                &x0[(size_t)(wavebase + t * 8) * 8 + lane]);   // = idx*8 + f8
            f32x4 w = wc0;
            float d01 = w.y*x.x - w.x*x.y;
            float d02 = w.z*x.x - w.x*x.z;
            float d03 = w.w*x.x - w.x*x.w;
            float d12 = w.z*x.y - w.y*x.z;
            float d13 = w.w*x.y - w.y*x.w;
            float d23 = w.w*x.z - w.z*x.w;
            cnt = 0.5f*(d01*d01 + d02*d02 + d03*d03 + d12*d12 + d13*d13 + d23*d23);
        }

        // ---- core1/core2: 8 x 128B dense segments per instruction ----
#pragma unroll
        for (int g = 0; g < 2; ++g) {
            const f32x4* xp = x12 + (size_t)g * (C * B * 32) + (size_t)idx * 32 + f8;
            float d01 = 0.f, d02 = 0.f, d03 = 0.f, d12 = 0.f, d13 = 0.f, d23 = 0.f;
#pragma unroll
            for (int p = 0; p < 4; ++p) {        // p = j, accumulates in-lane
                f32x4 x = __builtin_nontemporal_load(&xp[p * 8]);
                f32x4 w = wc12[g][p];
                d01 += w.y*x.x - w.x*x.y;
                d02 += w.z*x.x - w.x*x.z;
                d03 += w.w*x.x - w.x*x.w;
                d12 += w.z*x.y - w.y*x.z;
                d13 += w.w*x.y - w.y*x.w;
                d23 += w.w*x.z - w.z*x.w;
            }
            cnt += 0.5f*(d01*d01 + d02*d02 + d03*d03 + d12*d12 + d13*d13 + d23*d23);
        }

        // ---- reduce over s (8 lanes) ----
        cnt += __shfl_xor(cnt, 1);
        cnt += __shfl_xor(cnt, 2);
        cnt += __shfl_xor(cnt, 4);

        if (f8 == 0) {
            int c = idx >> 12;          // / 4096
            int b = idx & (B - 1);
            out[(size_t)b * C + c] = sqrtf(cnt + 384.0f * (EPS * EPS) + EPS);
        }
    }
}

extern "C" void kernel_launch(void* const* d_in, const int* in_sizes, int n_in,
                              void* d_out, int out_size, void* d_ws, size_t ws_size,
                              hipStream_t stream) {
    const f32x4* x0  = (const f32x4*)d_in[0];
    const f32x4* x12 = (const f32x4*)d_in[1];
    const f32x4* w0  = (const f32x4*)d_in[2];
    const f32x4* w12 = (const f32x4*)d_in[3];
    float* out = (float*)d_out;

    // 1536 blocks * 4 waves * 80 pairs = 491520 = C*B exactly; 6 blocks/CU.
    hipLaunchKernelGGL(ttfc_kernel, dim3(1536), dim3(256), 0, stream,
                       x0, x12, w0, w12, out);
}